// Round 3
// baseline (1690.246 us; speedup 1.0000x reference)
//
#include <hip/hip_runtime.h>

#define NB 16
#define NPTS 4096
#define NS 1024
#define NK 32
#define NCF 64

// All I/O is float32. Zero workspace bytes used. kNN parks its 32 indices
// (bit-cast to float) in the first 128B of each query's 512B output row;
// mlp_kernel reads them back and fully overwrites the row. Row ORDER of the
// 32 neighbors is irrelevant (max-pool) — only the index SET must be exact.
//
// REGISTER DISCIPLINE (r7-r14):
//  - The compiler refuses VGPR residency for the fps point arrays: plain
//    loads get sunk/remat'd into the loop (r12: VGPR 68, reload from L1
//    every step); an `asm "+v"` pin blocks remat but the allocator then
//    SPILLS to scratch instead of keeping 48 live VGPRs (r13: VGPR still
//    68, 834us > 603us — scratch reload is slower than L1 reload).
//  - R14 fix: park coords in AGPRs via explicit v_accvgpr_write_b32 and
//    read them back per step with volatile v_accvgpr_read_b32. Unified-file
//    pressure ~60 VGPR + 48 AGPR << 512, remat through asm impossible,
//    AGPR->VALU readback is 2 cyc/value vs ~750 cyc/step memory refetch.
//    volatile on the reads stops hoisting (hoist == 48 live VGPRs again).
//  - R12: knn = value-only med3 scan + threshold-recovery pass (exact set).
//  - R13: fps argmax = tournament tree; winning centroid coords ride the
//    LDS key exchange (one dependent LDS round per step instead of two).

#define F_INF __int_as_float(0x7f800000)

#define DPP_SHR1   0x111
#define DPP_SHR2   0x112
#define DPP_SHR4   0x114
#define DPP_SHR8   0x118
#define DPP_BCAST15 0x142
#define DPP_BCAST31 0x143

// one max step of a wave64 u64-key reduction via DPP (invalid lanes keep self)
#define DPP_MAX_STEP(cur, CTRL) do{ \
  int lo_=__builtin_amdgcn_update_dpp((int)(unsigned)(cur),(int)(unsigned)(cur),CTRL,0xF,0xF,false); \
  int hi_=__builtin_amdgcn_update_dpp((int)(unsigned)((cur)>>32),(int)(unsigned)((cur)>>32),CTRL,0xF,0xF,false); \
  unsigned long long nk_=(((unsigned long long)(unsigned)hi_)<<32)|(unsigned)lo_; \
  if (nk_>(cur)) (cur)=nk_; \
}while(0)

// ---------------- FPS: 1 block/batch, 256 thr (4 waves), DPP argmax ------
// key = (dist_bits<<32) | (4095-idx): u64 max == max dist, first index.
// Per-step serial chain: read coords from AGPR -> fused dist update+min ->
// tree argmax -> DPP -> lane63 publishes {key, centroid coords} -> barrier
// -> 4-way tournament. sxyz in LDS only for the lane63 candidate lookup +
// final output gather.
__global__ __launch_bounds__(256, 2) void fps_kernel(
  const float* __restrict__ xyz, float* __restrict__ out)
{
  __shared__ float sxyz[NPTS*3];
  __shared__ unsigned long long skey[2][4];
  __shared__ float4 scent[2][4];
  __shared__ int sfps[NS];
  const int b = blockIdx.x, tid = threadIdx.x;
  const int wave = tid>>6, lane = tid&63;
  const float* bp = xyz + (size_t)b*NPTS*3;

  { // stage xyz -> LDS (candidate lookup + output gather)
    const float4* src=(const float4*)bp;
    float4* dst=(float4*)sxyz;
    for (int i=tid;i<NPTS*3/4;i+=256) dst[i]=src[i];
  }
  // 16 points per thread, strided p=r*256+tid, parked in 48 AGPRs.
  // (p ascends with r => leftmost tree winner == smallest global index)
  float apx[16],apy[16],apz[16],dist[16];
  #pragma unroll
  for (int r=0;r<16;r++){
    int p=r*256+tid;
    float x=bp[p*3], y=bp[p*3+1], z=bp[p*3+2];
    asm volatile("v_accvgpr_write_b32 %0, %1" : "=a"(apx[r]) : "v"(x));
    asm volatile("v_accvgpr_write_b32 %0, %1" : "=a"(apy[r]) : "v"(y));
    asm volatile("v_accvgpr_write_b32 %0, %1" : "=a"(apz[r]) : "v"(z));
    dist[r]=1e10f;
  }
  __syncthreads();

  float cx=sxyz[0], cy=sxyz[1], cz=sxyz[2];   // seed centroid = point 0
  for (int s=0;s<NS;++s){
    // --- distance update; coords stream out of AGPRs (no memory) ---
    #pragma unroll
    for (int r=0;r<16;r++){
      float x,y,z;
      asm volatile("v_accvgpr_read_b32 %0, %1" : "=v"(x) : "a"(apx[r]));
      asm volatile("v_accvgpr_read_b32 %0, %1" : "=v"(y) : "a"(apy[r]));
      asm volatile("v_accvgpr_read_b32 %0, %1" : "=v"(z) : "a"(apz[r]));
      float dx=__fsub_rn(x,cx);
      float dy=__fsub_rn(y,cy);
      float dz=__fsub_rn(z,cz);
      float d2=__fadd_rn(__fadd_rn(__fmul_rn(dx,dx),__fmul_rn(dy,dy)),__fmul_rn(dz,dz));
      dist[r]=fminf(dist[r],d2);
    }
    // --- leftmost-max tournament (strict > keeps smallest slot) ---
    float v8[8]; int s8[8];
    #pragma unroll
    for (int i=0;i<8;i++){ bool g=dist[2*i+1]>dist[2*i]; v8[i]=g?dist[2*i+1]:dist[2*i]; s8[i]=g?(2*i+1):(2*i); }
    float v4[4]; int s4[4];
    #pragma unroll
    for (int i=0;i<4;i++){ bool g=v8[2*i+1]>v8[2*i]; v4[i]=g?v8[2*i+1]:v8[2*i]; s4[i]=g?s8[2*i+1]:s8[2*i]; }
    float v2[2]; int s2[2];
    #pragma unroll
    for (int i=0;i<2;i++){ bool g=v4[2*i+1]>v4[2*i]; v2[i]=g?v4[2*i+1]:v4[2*i]; s2[i]=g?s4[2*i+1]:s4[2*i]; }
    bool gf=v2[1]>v2[0];
    float bv=gf?v2[1]:v2[0];
    int bslot=gf?s2[1]:s2[0];

    int bidx=bslot*256+tid;
    unsigned long long cur=(((unsigned long long)__float_as_uint(bv))<<32)
                           |(unsigned)(4095-bidx);
    DPP_MAX_STEP(cur,DPP_SHR1);
    DPP_MAX_STEP(cur,DPP_SHR2);
    DPP_MAX_STEP(cur,DPP_SHR4);
    DPP_MAX_STEP(cur,DPP_SHR8);
    DPP_MAX_STEP(cur,DPP_BCAST15);
    DPP_MAX_STEP(cur,DPP_BCAST31);
    const int par=s&1;
    if (lane==63){
      int cand=4095-(int)(cur&0xFFFFFFFFu);
      float wx=sxyz[cand*3],wy=sxyz[cand*3+1],wz=sxyz[cand*3+2];
      skey[par][wave]=cur;
      scent[par][wave]=make_float4(wx,wy,wz,0.0f);
    }
    __syncthreads();
    // --- tournament over the 4 wave candidates; coords ride along ---
    unsigned long long k0=skey[par][0],k1=skey[par][1],k2=skey[par][2],k3=skey[par][3];
    float4 q0=scent[par][0],q1=scent[par][1],q2=scent[par][2],q3=scent[par][3];
    bool g01=k1>k0; unsigned long long ka=g01?k1:k0; float4 qa=g01?q1:q0;
    bool g23=k3>k2; unsigned long long kb=g23?k3:k2; float4 qb=g23?q3:q2;
    bool gab=kb>ka; unsigned long long km=gab?kb:ka; float4 qm=gab?qb:qa;
    cx=qm.x; cy=qm.y; cz=qm.z;
    if (tid==0) sfps[s]=4095-(int)(km&0xFFFFFFFFu);
  }
  __syncthreads();
  for (int s=tid;s<NS;s+=256){
    int p=sfps[s];
    size_t o=((size_t)b*NS+s)*3;
    out[o]=sxyz[p*3]; out[o+1]=sxyz[p*3+1]; out[o+2]=sxyz[p*3+2];
  }
}

// ---------------- kNN: 256 thr (4 waves), 16 queries/block ----------------
// 16 lanes/query scan interleaved 256-pt partitions from GLOBAL (L1/L2).
// Pass A: branch-free VALUE-ONLY sorted top-32 per lane (31 med3 + 1 min per
//   point; non-inserting d2 is a provable no-op on a sorted list).
// Merge: single dump (stride-33, conflict-free), 4->1 then 4->1 value merge
//   per query -> Tq = exact 32nd-smallest d2 + multiplicity e of Tq in top-32.
// Pass B: rescan with bit-identical d2; d2<Tq -> atomic-append index (order
//   irrelevant by contract), d2==Tq -> tie buffer; e smallest tie indices
//   complete the set (== lax.top_k stability). Exact index SET, any order.
__global__ __launch_bounds__(256, 4) void knn_kernel(
  const float* __restrict__ xyz, const float* __restrict__ newxyz,
  float* __restrict__ out2)
{
  __shared__ float sdump[256*33];   // 33.0 KB, per-lane sorted values
  __shared__ float sl1[64*33];      // 8.25 KB, level-1 merged values
  __shared__ float sTq[16];
  __shared__ int   sE[16];
  __shared__ int   sCnt[16];
  __shared__ int   sTCnt[16];
  __shared__ int   sIdx[16][32];
  __shared__ int   sTie[16][48];
  const int tid=threadIdx.x;
  const int wave=tid>>6, lane=tid&63;
  const int qw=lane>>4;               // query-within-wave 0..3
  const int part=lane&15;             // partition 0..15
  const int ql=wave*4+qw;             // query-within-block 0..15
  const int gq=blockIdx.x*16+ql;
  const int b=gq>>10;
  const float* base=xyz+(size_t)b*NPTS*3;

  float ax=newxyz[(size_t)gq*3],ay=newxyz[(size_t)gq*3+1],az=newxyz[(size_t)gq*3+2];
  float a2=__fadd_rn(__fadd_rn(__fmul_rn(ax,ax),__fmul_rn(ay,ay)),__fmul_rn(az,az));

  float kD[NK];
  #pragma unroll
  for (int p=0;p<NK;p++) kD[p]=F_INF;

  #pragma unroll 2
  for (int t=0;t<NPTS/16;++t){
    int n=(t<<4)|part;
    float bx=base[n*3],by=base[n*3+1],bz=base[n*3+2];
    float b2=__fadd_rn(__fadd_rn(__fmul_rn(bx,bx),__fmul_rn(by,by)),__fmul_rn(bz,bz));
    float ab=__fadd_rn(__fadd_rn(__fmul_rn(ax,bx),__fmul_rn(ay,by)),__fmul_rn(az,bz));
    float tt=__fadd_rn(__fsub_rn(a2,__fmul_rn(2.0f,ab)),b2);
    float d2=fmaxf(tt,0.0f);
    // branch-free sorted insert (values only). Descending p reads kD[p-1]
    // before it is rewritten; if d2 >= kD[31] every med3 is an identity.
    #pragma unroll
    for (int p=NK-1;p>0;--p)
      kD[p]=__builtin_amdgcn_fmed3f(kD[p-1],d2,kD[p]);
    kD[0]=fminf(kD[0],d2);
  }

  // dump per-lane sorted values (stride 33 => lane-conflict-free b32 writes)
  #pragma unroll
  for (int p=0;p<NK;p++) sdump[tid*33+p]=kD[p];
  __syncthreads();

  // level 1: 64 threads, each merges 4 lane-lists of one query
  if (tid<64){
    int qq=tid>>2, g=tid&3;
    int rbase=(qq>>2)*64+(qq&3)*16+g*4;   // tid of first contributing lane
    const float* r0=sdump+(size_t)(rbase+0)*33;
    const float* r1=sdump+(size_t)(rbase+1)*33;
    const float* r2=sdump+(size_t)(rbase+2)*33;
    const float* r3=sdump+(size_t)(rbase+3)*33;
    float* o=sl1+(size_t)tid*33;
    int h0=0,h1=0,h2=0,h3=0;
    float c0=r0[0],c1=r1[0],c2=r2[0],c3=r3[0];
    #pragma unroll 1
    for (int i=0;i<NK;++i){
      bool s01=c1<c0; float m01=s01?c1:c0;
      bool s23=c3<c2; float m23=s23?c3:c2;
      bool sm=m23<m01; float m=sm?m23:m01;
      o[i]=m;
      int w=sm?(s23?3:2):(s01?1:0);
      if (w==0){h0++; c0=(h0<NK)?r0[h0]:F_INF;}
      else if (w==1){h1++; c1=(h1<NK)?r1[h1]:F_INF;}
      else if (w==2){h2++; c2=(h2<NK)?r2[h2]:F_INF;}
      else {h3++; c3=(h3<NK)?r3[h3]:F_INF;}
    }
  }
  __syncthreads();

  // level 2: 16 threads -> Tq (32nd smallest) + multiplicity e within top-32
  if (tid<16){
    const float* r0=sl1+(size_t)(tid*4+0)*33;
    const float* r1=sl1+(size_t)(tid*4+1)*33;
    const float* r2=sl1+(size_t)(tid*4+2)*33;
    const float* r3=sl1+(size_t)(tid*4+3)*33;
    int h0=0,h1=0,h2=0,h3=0;
    float c0=r0[0],c1=r1[0],c2=r2[0],c3=r3[0];
    float prev=-1.0f; int run=0;
    #pragma unroll 1
    for (int i=0;i<NK;++i){
      bool s01=c1<c0; float m01=s01?c1:c0;
      bool s23=c3<c2; float m23=s23?c3:c2;
      bool sm=m23<m01; float m=sm?m23:m01;
      if (m==prev) run++; else {prev=m; run=1;}
      int w=sm?(s23?3:2):(s01?1:0);
      if (w==0){h0++; c0=(h0<NK)?r0[h0]:F_INF;}
      else if (w==1){h1++; c1=(h1<NK)?r1[h1]:F_INF;}
      else if (w==2){h2++; c2=(h2<NK)?r2[h2]:F_INF;}
      else {h3++; c3=(h3<NK)?r3[h3]:F_INF;}
    }
    sTq[tid]=prev; sE[tid]=run;
    sCnt[tid]=0; sTCnt[tid]=0;
  }
  __syncthreads();

  // pass B: recovery rescan with bit-identical arithmetic
  {
    const float Tq=sTq[ql];
    #pragma unroll 2
    for (int t=0;t<NPTS/16;++t){
      int n=(t<<4)|part;
      float bx=base[n*3],by=base[n*3+1],bz=base[n*3+2];
      float b2=__fadd_rn(__fadd_rn(__fmul_rn(bx,bx),__fmul_rn(by,by)),__fmul_rn(bz,bz));
      float ab=__fadd_rn(__fadd_rn(__fmul_rn(ax,bx),__fmul_rn(ay,by)),__fmul_rn(az,bz));
      float tt=__fadd_rn(__fsub_rn(a2,__fmul_rn(2.0f,ab)),b2);
      float d2=fmaxf(tt,0.0f);
      if (d2<Tq){
        int pos=atomicAdd(&sCnt[ql],1);
        if (pos<32) sIdx[ql][pos]=n;        // pos<=30 guaranteed (c<=31)
      } else if (d2==Tq){
        int tp=atomicAdd(&sTCnt[ql],1);
        if (tp<48) sTie[ql][tp]=n;          // >=e entries always land here
      }
    }
  }
  __syncthreads();

  // finalize: append the e smallest tie indices (== top_k stable tie-break)
  if (tid<16){
    int e=sE[tid], c=sCnt[tid];
    int tn=sTCnt[tid]; if (tn>48) tn=48;
    for (int j=0;j<e;++j){
      int bm=0x7FFFFFFF, bi=0;
      for (int i=0;i<tn;++i){ int v=sTie[tid][i]; if (v<bm){bm=v;bi=i;} }
      sTie[tid][bi]=0x7FFFFFFF;
      if (c+j<32) sIdx[tid][c+j]=bm;
    }
  }
  __syncthreads();

  for (int i=tid;i<512;i+=256){
    int q=i>>5, k=i&31;
    out2[(size_t)(blockIdx.x*16+q)*128+k]=__int_as_float(sIdx[q][k]);
  }
}

// ---------------- fused group + MLP(3) + maxpool --------------------------
// 128 threads = 4 queries x 32 neighbor rows. float4 weight loads.
__global__ __launch_bounds__(128, 3) void mlp_kernel(
  const float* __restrict__ feat, const float* __restrict__ xyz,
  const float* __restrict__ newxyz,
  const float* __restrict__ W0,const float* __restrict__ b0,
  const float* __restrict__ g0,const float* __restrict__ be0,
  const float* __restrict__ m0,const float* __restrict__ v0,
  const float* __restrict__ W1,const float* __restrict__ b1,
  const float* __restrict__ g1,const float* __restrict__ be1,
  const float* __restrict__ m1,const float* __restrict__ v1,
  const float* __restrict__ W2,const float* __restrict__ b2,
  const float* __restrict__ g2,const float* __restrict__ be2,
  const float* __restrict__ m2,const float* __restrict__ v2,
  float* __restrict__ out2)
{
  __shared__ float sX[128*67];
  const int tid=threadIdx.x;
  const int q=blockIdx.x*4+(tid>>5);
  const int k=tid&31;
  const int b=q>>10;
  const int pt=__float_as_int(out2[(size_t)q*128+k]);

  float* myx=sX+tid*67;
  {
    const float* nx=newxyz+(size_t)q*3;
    const float* pp=xyz+((size_t)b*NPTS+pt)*3;
    myx[0]=pp[0]-nx[0]; myx[1]=pp[1]-nx[1]; myx[2]=pp[2]-nx[2];
    const float4* fp=(const float4*)(feat+((size_t)b*NPTS+pt)*NCF);
    #pragma unroll
    for (int i=0;i<16;i++){
      float4 u=fp[i]; float* d=myx+3+i*4;
      d[0]=u.x; d[1]=u.y; d[2]=u.z; d[3]=u.w;
    }
  }
  float acc[64];
  // layer 1: 67 -> 64
  #pragma unroll
  for (int c=0;c<64;c++) acc[c]=b0[c];
  #pragma unroll 2
  for (int j=0;j<67;++j){
    float xj=myx[j];
    const float4* wr=(const float4*)(W0+j*64);
    #pragma unroll
    for (int c4=0;c4<16;c4++){
      float4 w=wr[c4];
      acc[c4*4+0]=fmaf(xj,w.x,acc[c4*4+0]);
      acc[c4*4+1]=fmaf(xj,w.y,acc[c4*4+1]);
      acc[c4*4+2]=fmaf(xj,w.z,acc[c4*4+2]);
      acc[c4*4+3]=fmaf(xj,w.w,acc[c4*4+3]);
    }
  }
  #pragma unroll
  for (int c=0;c<64;c++){
    float A=g0[c]*rsqrtf(v0[c]+1e-3f);
    myx[c]=fmaf(A,fmaxf(acc[c],0.0f),be0[c]-m0[c]*A);
  }
  // layer 2: 64 -> 64
  #pragma unroll
  for (int c=0;c<64;c++) acc[c]=b1[c];
  #pragma unroll 2
  for (int j=0;j<64;++j){
    float xj=myx[j];
    const float4* wr=(const float4*)(W1+j*64);
    #pragma unroll
    for (int c4=0;c4<16;c4++){
      float4 w=wr[c4];
      acc[c4*4+0]=fmaf(xj,w.x,acc[c4*4+0]);
      acc[c4*4+1]=fmaf(xj,w.y,acc[c4*4+1]);
      acc[c4*4+2]=fmaf(xj,w.z,acc[c4*4+2]);
      acc[c4*4+3]=fmaf(xj,w.w,acc[c4*4+3]);
    }
  }
  #pragma unroll
  for (int c=0;c<64;c++){
    float A=g1[c]*rsqrtf(v1[c]+1e-3f);
    myx[c]=fmaf(A,fmaxf(acc[c],0.0f),be1[c]-m1[c]*A);
  }
  // layer 3: 64 -> 128, two 64-col chunks (keeps VGPR low)
  #pragma unroll 1
  for (int ch=0;ch<2;++ch){
    const int co=ch*64;
    #pragma unroll
    for (int c=0;c<64;c++) acc[c]=b2[co+c];
    #pragma unroll 2
    for (int j=0;j<64;++j){
      float xj=myx[j];
      const float4* wr=(const float4*)(W2+j*128+co);
      #pragma unroll
      for (int c4=0;c4<16;c4++){
        float4 w=wr[c4];
        acc[c4*4+0]=fmaf(xj,w.x,acc[c4*4+0]);
        acc[c4*4+1]=fmaf(xj,w.y,acc[c4*4+1]);
        acc[c4*4+2]=fmaf(xj,w.z,acc[c4*4+2]);
        acc[c4*4+3]=fmaf(xj,w.w,acc[c4*4+3]);
      }
    }
    #pragma unroll
    for (int c=0;c<64;c++){
      float A=g2[co+c]*rsqrtf(v2[co+c]+1e-3f);
      float v=fmaf(A,fmaxf(acc[c],0.0f),be2[co+c]-m2[co+c]*A);
      v=fmaxf(v,__shfl_xor(v,1));
      v=fmaxf(v,__shfl_xor(v,2));
      v=fmaxf(v,__shfl_xor(v,4));
      v=fmaxf(v,__shfl_xor(v,8));
      v=fmaxf(v,__shfl_xor(v,16));
      acc[c]=v;
    }
    if (k==0){
      float4* op=(float4*)(out2+(size_t)q*128+co);
      #pragma unroll
      for (int c=0;c<64;c+=4)
        op[c/4]=make_float4(acc[c],acc[c+1],acc[c+2],acc[c+3]);
    }
  }
}

extern "C" void kernel_launch(void* const* d_in, const int* in_sizes, int n_in,
                              void* d_out, int out_size, void* d_ws, size_t ws_size,
                              hipStream_t stream)
{
  const float* xyz=(const float*)d_in[0];
  const float* feat=(const float*)d_in[1];
  float* out=(float*)d_out;
  float* out2=out+(size_t)NB*NS*3;     // pooled-feature region
  (void)d_ws; (void)ws_size;

  fps_kernel<<<NB,256,0,stream>>>(xyz,out);
  knn_kernel<<<NB*NS/16,256,0,stream>>>(xyz,out,out2);
  mlp_kernel<<<NB*NS/4,128,0,stream>>>(feat,xyz,out,
    (const float*)d_in[2],(const float*)d_in[3],
    (const float*)d_in[4],(const float*)d_in[5],
    (const float*)d_in[6],(const float*)d_in[7],
    (const float*)d_in[8],(const float*)d_in[9],
    (const float*)d_in[10],(const float*)d_in[11],
    (const float*)d_in[12],(const float*)d_in[13],
    (const float*)d_in[14],(const float*)d_in[15],
    (const float*)d_in[16],(const float*)d_in[17],
    (const float*)d_in[18],(const float*)d_in[19],
    out2);
}

// Round 4
// 1411.045 us; speedup vs baseline: 1.1979x; 1.1979x over previous
//
#include <hip/hip_runtime.h>

#define NB 16
#define NPTS 4096
#define NS 1024
#define NK 32
#define NCF 64

// All I/O is float32. Zero workspace bytes used. kNN parks its 32 indices
// (bit-cast to float) in the first 128B of each query's 512B output row;
// mlp_kernel reads them back and fully overwrites the row. Row ORDER of the
// 32 neighbors is irrelevant (max-pool) — only the index SET must be exact.
//
// SCRATCH: fps uses the out2 region (8MB) as scratch for a padded float4
// copy of xyz (1MB, written by pack_kernel). Legal because knn (which runs
// after fps) only WRITES out2 heads, and mlp overwrites every byte of out2.
//
// REGISTER DISCIPLINE (r7-r15) — the fps coord-residency saga, closed:
//  - plain loads: compiler sinks/remats into the loop, streams from L1
//    every step (r12: VGPR 68, 603us; 48 scalar VMEM/thread/step).
//  - asm "+v" pin: blocks remat, allocator spills to scratch instead
//    (r13: 834us). AGPR park + volatile reads: the 48 volatile asms
//    serialize the loop (r14: 943us).
//  - R15 verdict: STOP fighting residency. Accept the L1 stream but cut
//    VMEM inst count 3x via packed float4 loads (pack_kernel prologue),
//    and double waves/SIMD (512 thr) so load latency overlaps compute.

#define F_INF __int_as_float(0x7f800000)

#define DPP_SHR1   0x111
#define DPP_SHR2   0x112
#define DPP_SHR4   0x114
#define DPP_SHR8   0x118
#define DPP_BCAST15 0x142
#define DPP_BCAST31 0x143

// one max step of a wave64 u64-key reduction via DPP (invalid lanes keep self)
#define DPP_MAX_STEP(cur, CTRL) do{ \
  int lo_=__builtin_amdgcn_update_dpp((int)(unsigned)(cur),(int)(unsigned)(cur),CTRL,0xF,0xF,false); \
  int hi_=__builtin_amdgcn_update_dpp((int)(unsigned)((cur)>>32),(int)(unsigned)((cur)>>32),CTRL,0xF,0xF,false); \
  unsigned long long nk_=(((unsigned long long)(unsigned)hi_)<<32)|(unsigned)lo_; \
  if (nk_>(cur)) (cur)=nk_; \
}while(0)

// ---------------- pack: xyz (12B stride) -> padded float4 scratch ---------
__global__ void pack_kernel(const float* __restrict__ xyz, float4* __restrict__ pk)
{
  int i=blockIdx.x*1024+threadIdx.x;
  if (i<NB*NPTS)
    pk[i]=make_float4(xyz[(size_t)i*3],xyz[(size_t)i*3+1],xyz[(size_t)i*3+2],0.0f);
}

// ---------------- FPS: 1 block/batch, 512 thr (8 waves), DPP argmax ------
// key = (dist_bits<<32) | (4095-idx): u64 max == max dist, first index.
// Per-step chain: 8x global_load_dwordx4 (L1/L2 stream, latency overlapped
// across 2 waves/SIMD) -> fused dist update+min -> 3-level tournament ->
// DPP -> lane63 publishes key -> barrier -> every thread max-trees the 8
// wave keys (uniform LDS broadcast) -> centroid = one ds_read_b128 from
// padded LDS copy. One barrier, one dependent LDS round per step.
__global__ __launch_bounds__(512, 2) void fps_kernel(
  const float4* __restrict__ pk, float* __restrict__ out)
{
  __shared__ float4 sp[NPTS];               // 64KB padded copy
  __shared__ unsigned long long skey[2][8];
  __shared__ int sfps[NS];
  const int b=blockIdx.x, tid=threadIdx.x;
  const int wave=tid>>6, lane=tid&63;
  const float4* bpk=pk+(size_t)b*NPTS;

  for (int i=tid;i<NPTS;i+=512) sp[i]=bpk[i];
  float dist[8];
  #pragma unroll
  for (int r=0;r<8;r++) dist[r]=1e10f;
  __syncthreads();

  float4 cseed=sp[0];
  float cx=cseed.x, cy=cseed.y, cz=cseed.z;   // seed centroid = point 0
  for (int s=0;s<NS;++s){
    // --- distance update: 8 packed loads (p = r*512+tid, ascending in r
    //     => leftmost tree winner == smallest global index) ---
    #pragma unroll
    for (int r=0;r<8;r++){
      float4 q=bpk[r*512+tid];
      float dx=__fsub_rn(q.x,cx);
      float dy=__fsub_rn(q.y,cy);
      float dz=__fsub_rn(q.z,cz);
      float d2=__fadd_rn(__fadd_rn(__fmul_rn(dx,dx),__fmul_rn(dy,dy)),__fmul_rn(dz,dz));
      dist[r]=fminf(dist[r],d2);
    }
    // --- leftmost-max tournament (strict > keeps smallest slot) ---
    float v4_[4]; int s4_[4];
    #pragma unroll
    for (int i=0;i<4;i++){ bool g=dist[2*i+1]>dist[2*i]; v4_[i]=g?dist[2*i+1]:dist[2*i]; s4_[i]=g?(2*i+1):(2*i); }
    float v2_[2]; int s2_[2];
    #pragma unroll
    for (int i=0;i<2;i++){ bool g=v4_[2*i+1]>v4_[2*i]; v2_[i]=g?v4_[2*i+1]:v4_[2*i]; s2_[i]=g?s4_[2*i+1]:s4_[2*i]; }
    bool gf=v2_[1]>v2_[0];
    float bv=gf?v2_[1]:v2_[0];
    int bslot=gf?s2_[1]:s2_[0];

    int bidx=bslot*512+tid;
    unsigned long long cur=(((unsigned long long)__float_as_uint(bv))<<32)
                           |(unsigned)(4095-bidx);
    DPP_MAX_STEP(cur,DPP_SHR1);
    DPP_MAX_STEP(cur,DPP_SHR2);
    DPP_MAX_STEP(cur,DPP_SHR4);
    DPP_MAX_STEP(cur,DPP_SHR8);
    DPP_MAX_STEP(cur,DPP_BCAST15);
    DPP_MAX_STEP(cur,DPP_BCAST31);
    const int par=s&1;
    if (lane==63) skey[par][wave]=cur;
    __syncthreads();
    // --- every thread: max-tree over the 8 wave keys (uniform broadcast) ---
    unsigned long long k0=skey[par][0],k1=skey[par][1],k2=skey[par][2],k3=skey[par][3];
    unsigned long long k4=skey[par][4],k5=skey[par][5],k6=skey[par][6],k7=skey[par][7];
    unsigned long long a0=k0>k1?k0:k1, a1=k2>k3?k2:k3, a2=k4>k5?k4:k5, a3=k6>k7?k6:k7;
    unsigned long long b0=a0>a1?a0:a1, b1=a2>a3?a2:a3;
    unsigned long long m=b0>b1?b0:b1;
    int far=4095-(int)(m&0xFFFFFFFFu);
    float4 cc=sp[far];                       // one b128, uniform broadcast
    cx=cc.x; cy=cc.y; cz=cc.z;
    if (tid==0) sfps[s]=far;
  }
  __syncthreads();
  for (int s=tid;s<NS;s+=512){
    int p=sfps[s];
    size_t o=((size_t)b*NS+s)*3;
    float4 pp=sp[p];
    out[o]=pp.x; out[o+1]=pp.y; out[o+2]=pp.z;
  }
}

// ---------------- kNN: 256 thr (4 waves), 16 queries/block ----------------
// 16 lanes/query scan interleaved 256-pt partitions from GLOBAL (L1/L2).
// Pass A: branch-free VALUE-ONLY sorted top-32 per lane (31 med3 + 1 min per
//   point; non-inserting d2 is a provable no-op on a sorted list).
// Merge: single dump (stride-33, conflict-free), 4->1 then 4->1 value merge
//   per query -> Tq = exact 32nd-smallest d2 + multiplicity e of Tq in top-32.
// Pass B: rescan with bit-identical d2; d2<Tq -> atomic-append index (order
//   irrelevant by contract), d2==Tq -> tie buffer; e smallest tie indices
//   complete the set (== lax.top_k stability). Exact index SET, any order.
__global__ __launch_bounds__(256, 4) void knn_kernel(
  const float* __restrict__ xyz, const float* __restrict__ newxyz,
  float* __restrict__ out2)
{
  __shared__ float sdump[256*33];   // 33.0 KB, per-lane sorted values
  __shared__ float sl1[64*33];      // 8.25 KB, level-1 merged values
  __shared__ float sTq[16];
  __shared__ int   sE[16];
  __shared__ int   sCnt[16];
  __shared__ int   sTCnt[16];
  __shared__ int   sIdx[16][32];
  __shared__ int   sTie[16][48];
  const int tid=threadIdx.x;
  const int wave=tid>>6, lane=tid&63;
  const int qw=lane>>4;               // query-within-wave 0..3
  const int part=lane&15;             // partition 0..15
  const int ql=wave*4+qw;             // query-within-block 0..15
  const int gq=blockIdx.x*16+ql;
  const int b=gq>>10;
  const float* base=xyz+(size_t)b*NPTS*3;

  float ax=newxyz[(size_t)gq*3],ay=newxyz[(size_t)gq*3+1],az=newxyz[(size_t)gq*3+2];
  float a2=__fadd_rn(__fadd_rn(__fmul_rn(ax,ax),__fmul_rn(ay,ay)),__fmul_rn(az,az));

  float kD[NK];
  #pragma unroll
  for (int p=0;p<NK;p++) kD[p]=F_INF;

  #pragma unroll 2
  for (int t=0;t<NPTS/16;++t){
    int n=(t<<4)|part;
    float bx=base[n*3],by=base[n*3+1],bz=base[n*3+2];
    float b2=__fadd_rn(__fadd_rn(__fmul_rn(bx,bx),__fmul_rn(by,by)),__fmul_rn(bz,bz));
    float ab=__fadd_rn(__fadd_rn(__fmul_rn(ax,bx),__fmul_rn(ay,by)),__fmul_rn(az,bz));
    float tt=__fadd_rn(__fsub_rn(a2,__fmul_rn(2.0f,ab)),b2);
    float d2=fmaxf(tt,0.0f);
    // branch-free sorted insert (values only). Descending p reads kD[p-1]
    // before it is rewritten; if d2 >= kD[31] every med3 is an identity.
    #pragma unroll
    for (int p=NK-1;p>0;--p)
      kD[p]=__builtin_amdgcn_fmed3f(kD[p-1],d2,kD[p]);
    kD[0]=fminf(kD[0],d2);
  }

  // dump per-lane sorted values (stride 33 => lane-conflict-free b32 writes)
  #pragma unroll
  for (int p=0;p<NK;p++) sdump[tid*33+p]=kD[p];
  __syncthreads();

  // level 1: 64 threads, each merges 4 lane-lists of one query
  if (tid<64){
    int qq=tid>>2, g=tid&3;
    int rbase=(qq>>2)*64+(qq&3)*16+g*4;   // tid of first contributing lane
    const float* r0=sdump+(size_t)(rbase+0)*33;
    const float* r1=sdump+(size_t)(rbase+1)*33;
    const float* r2=sdump+(size_t)(rbase+2)*33;
    const float* r3=sdump+(size_t)(rbase+3)*33;
    float* o=sl1+(size_t)tid*33;
    int h0=0,h1=0,h2=0,h3=0;
    float c0=r0[0],c1=r1[0],c2=r2[0],c3=r3[0];
    #pragma unroll 1
    for (int i=0;i<NK;++i){
      bool s01=c1<c0; float m01=s01?c1:c0;
      bool s23=c3<c2; float m23=s23?c3:c2;
      bool sm=m23<m01; float m=sm?m23:m01;
      o[i]=m;
      int w=sm?(s23?3:2):(s01?1:0);
      if (w==0){h0++; c0=(h0<NK)?r0[h0]:F_INF;}
      else if (w==1){h1++; c1=(h1<NK)?r1[h1]:F_INF;}
      else if (w==2){h2++; c2=(h2<NK)?r2[h2]:F_INF;}
      else {h3++; c3=(h3<NK)?r3[h3]:F_INF;}
    }
  }
  __syncthreads();

  // level 2: 16 threads -> Tq (32nd smallest) + multiplicity e within top-32
  if (tid<16){
    const float* r0=sl1+(size_t)(tid*4+0)*33;
    const float* r1=sl1+(size_t)(tid*4+1)*33;
    const float* r2=sl1+(size_t)(tid*4+2)*33;
    const float* r3=sl1+(size_t)(tid*4+3)*33;
    int h0=0,h1=0,h2=0,h3=0;
    float c0=r0[0],c1=r1[0],c2=r2[0],c3=r3[0];
    float prev=-1.0f; int run=0;
    #pragma unroll 1
    for (int i=0;i<NK;++i){
      bool s01=c1<c0; float m01=s01?c1:c0;
      bool s23=c3<c2; float m23=s23?c3:c2;
      bool sm=m23<m01; float m=sm?m23:m01;
      if (m==prev) run++; else {prev=m; run=1;}
      int w=sm?(s23?3:2):(s01?1:0);
      if (w==0){h0++; c0=(h0<NK)?r0[h0]:F_INF;}
      else if (w==1){h1++; c1=(h1<NK)?r1[h1]:F_INF;}
      else if (w==2){h2++; c2=(h2<NK)?r2[h2]:F_INF;}
      else {h3++; c3=(h3<NK)?r3[h3]:F_INF;}
    }
    sTq[tid]=prev; sE[tid]=run;
    sCnt[tid]=0; sTCnt[tid]=0;
  }
  __syncthreads();

  // pass B: recovery rescan with bit-identical arithmetic
  {
    const float Tq=sTq[ql];
    #pragma unroll 2
    for (int t=0;t<NPTS/16;++t){
      int n=(t<<4)|part;
      float bx=base[n*3],by=base[n*3+1],bz=base[n*3+2];
      float b2=__fadd_rn(__fadd_rn(__fmul_rn(bx,bx),__fmul_rn(by,by)),__fmul_rn(bz,bz));
      float ab=__fadd_rn(__fadd_rn(__fmul_rn(ax,bx),__fmul_rn(ay,by)),__fmul_rn(az,bz));
      float tt=__fadd_rn(__fsub_rn(a2,__fmul_rn(2.0f,ab)),b2);
      float d2=fmaxf(tt,0.0f);
      if (d2<Tq){
        int pos=atomicAdd(&sCnt[ql],1);
        if (pos<32) sIdx[ql][pos]=n;        // pos<=30 guaranteed (c<=31)
      } else if (d2==Tq){
        int tp=atomicAdd(&sTCnt[ql],1);
        if (tp<48) sTie[ql][tp]=n;          // >=e entries always land here
      }
    }
  }
  __syncthreads();

  // finalize: append the e smallest tie indices (== top_k stable tie-break)
  if (tid<16){
    int e=sE[tid], c=sCnt[tid];
    int tn=sTCnt[tid]; if (tn>48) tn=48;
    for (int j=0;j<e;++j){
      int bm=0x7FFFFFFF, bi=0;
      for (int i=0;i<tn;++i){ int v=sTie[tid][i]; if (v<bm){bm=v;bi=i;} }
      sTie[tid][bi]=0x7FFFFFFF;
      if (c+j<32) sIdx[tid][c+j]=bm;
    }
  }
  __syncthreads();

  for (int i=tid;i<512;i+=256){
    int q=i>>5, k=i&31;
    out2[(size_t)(blockIdx.x*16+q)*128+k]=__int_as_float(sIdx[q][k]);
  }
}

// ---------------- fused group + MLP(3) + maxpool --------------------------
// 128 threads = 4 queries x 32 neighbor rows. float4 weight loads.
__global__ __launch_bounds__(128, 3) void mlp_kernel(
  const float* __restrict__ feat, const float* __restrict__ xyz,
  const float* __restrict__ newxyz,
  const float* __restrict__ W0,const float* __restrict__ b0,
  const float* __restrict__ g0,const float* __restrict__ be0,
  const float* __restrict__ m0,const float* __restrict__ v0,
  const float* __restrict__ W1,const float* __restrict__ b1,
  const float* __restrict__ g1,const float* __restrict__ be1,
  const float* __restrict__ m1,const float* __restrict__ v1,
  const float* __restrict__ W2,const float* __restrict__ b2,
  const float* __restrict__ g2,const float* __restrict__ be2,
  const float* __restrict__ m2,const float* __restrict__ v2,
  float* __restrict__ out2)
{
  __shared__ float sX[128*67];
  const int tid=threadIdx.x;
  const int q=blockIdx.x*4+(tid>>5);
  const int k=tid&31;
  const int b=q>>10;
  const int pt=__float_as_int(out2[(size_t)q*128+k]);

  float* myx=sX+tid*67;
  {
    const float* nx=newxyz+(size_t)q*3;
    const float* pp=xyz+((size_t)b*NPTS+pt)*3;
    myx[0]=pp[0]-nx[0]; myx[1]=pp[1]-nx[1]; myx[2]=pp[2]-nx[2];
    const float4* fp=(const float4*)(feat+((size_t)b*NPTS+pt)*NCF);
    #pragma unroll
    for (int i=0;i<16;i++){
      float4 u=fp[i]; float* d=myx+3+i*4;
      d[0]=u.x; d[1]=u.y; d[2]=u.z; d[3]=u.w;
    }
  }
  float acc[64];
  // layer 1: 67 -> 64
  #pragma unroll
  for (int c=0;c<64;c++) acc[c]=b0[c];
  #pragma unroll 2
  for (int j=0;j<67;++j){
    float xj=myx[j];
    const float4* wr=(const float4*)(W0+j*64);
    #pragma unroll
    for (int c4=0;c4<16;c4++){
      float4 w=wr[c4];
      acc[c4*4+0]=fmaf(xj,w.x,acc[c4*4+0]);
      acc[c4*4+1]=fmaf(xj,w.y,acc[c4*4+1]);
      acc[c4*4+2]=fmaf(xj,w.z,acc[c4*4+2]);
      acc[c4*4+3]=fmaf(xj,w.w,acc[c4*4+3]);
    }
  }
  #pragma unroll
  for (int c=0;c<64;c++){
    float A=g0[c]*rsqrtf(v0[c]+1e-3f);
    myx[c]=fmaf(A,fmaxf(acc[c],0.0f),be0[c]-m0[c]*A);
  }
  // layer 2: 64 -> 64
  #pragma unroll
  for (int c=0;c<64;c++) acc[c]=b1[c];
  #pragma unroll 2
  for (int j=0;j<64;++j){
    float xj=myx[j];
    const float4* wr=(const float4*)(W1+j*64);
    #pragma unroll
    for (int c4=0;c4<16;c4++){
      float4 w=wr[c4];
      acc[c4*4+0]=fmaf(xj,w.x,acc[c4*4+0]);
      acc[c4*4+1]=fmaf(xj,w.y,acc[c4*4+1]);
      acc[c4*4+2]=fmaf(xj,w.z,acc[c4*4+2]);
      acc[c4*4+3]=fmaf(xj,w.w,acc[c4*4+3]);
    }
  }
  #pragma unroll
  for (int c=0;c<64;c++){
    float A=g1[c]*rsqrtf(v1[c]+1e-3f);
    myx[c]=fmaf(A,fmaxf(acc[c],0.0f),be1[c]-m1[c]*A);
  }
  // layer 3: 64 -> 128, two 64-col chunks (keeps VGPR low)
  #pragma unroll 1
  for (int ch=0;ch<2;++ch){
    const int co=ch*64;
    #pragma unroll
    for (int c=0;c<64;c++) acc[c]=b2[co+c];
    #pragma unroll 2
    for (int j=0;j<64;++j){
      float xj=myx[j];
      const float4* wr=(const float4*)(W2+j*128+co);
      #pragma unroll
      for (int c4=0;c4<16;c4++){
        float4 w=wr[c4];
        acc[c4*4+0]=fmaf(xj,w.x,acc[c4*4+0]);
        acc[c4*4+1]=fmaf(xj,w.y,acc[c4*4+1]);
        acc[c4*4+2]=fmaf(xj,w.z,acc[c4*4+2]);
        acc[c4*4+3]=fmaf(xj,w.w,acc[c4*4+3]);
      }
    }
    #pragma unroll
    for (int c=0;c<64;c++){
      float A=g2[co+c]*rsqrtf(v2[co+c]+1e-3f);
      float v=fmaf(A,fmaxf(acc[c],0.0f),be2[co+c]-m2[co+c]*A);
      v=fmaxf(v,__shfl_xor(v,1));
      v=fmaxf(v,__shfl_xor(v,2));
      v=fmaxf(v,__shfl_xor(v,4));
      v=fmaxf(v,__shfl_xor(v,8));
      v=fmaxf(v,__shfl_xor(v,16));
      acc[c]=v;
    }
    if (k==0){
      float4* op=(float4*)(out2+(size_t)q*128+co);
      #pragma unroll
      for (int c=0;c<64;c+=4)
        op[c/4]=make_float4(acc[c],acc[c+1],acc[c+2],acc[c+3]);
    }
  }
}

extern "C" void kernel_launch(void* const* d_in, const int* in_sizes, int n_in,
                              void* d_out, int out_size, void* d_ws, size_t ws_size,
                              hipStream_t stream)
{
  const float* xyz=(const float*)d_in[0];
  const float* feat=(const float*)d_in[1];
  float* out=(float*)d_out;
  float* out2=out+(size_t)NB*NS*3;     // pooled-feature region
  float4* pk=(float4*)out2;            // fps scratch (overwritten by knn/mlp)
  (void)d_ws; (void)ws_size;

  pack_kernel<<<(NB*NPTS+1023)/1024,1024,0,stream>>>(xyz,pk);
  fps_kernel<<<NB,512,0,stream>>>(pk,out);
  knn_kernel<<<NB*NS/16,256,0,stream>>>(xyz,out,out2);
  mlp_kernel<<<NB*NS/4,128,0,stream>>>(feat,xyz,out,
    (const float*)d_in[2],(const float*)d_in[3],
    (const float*)d_in[4],(const float*)d_in[5],
    (const float*)d_in[6],(const float*)d_in[7],
    (const float*)d_in[8],(const float*)d_in[9],
    (const float*)d_in[10],(const float*)d_in[11],
    (const float*)d_in[12],(const float*)d_in[13],
    (const float*)d_in[14],(const float*)d_in[15],
    (const float*)d_in[16],(const float*)d_in[17],
    (const float*)d_in[18],(const float*)d_in[19],
    out2);
}